// Round 1
// baseline (706.349 us; speedup 1.0000x reference)
//
#include <hip/hip_runtime.h>

// Multi-scale deformable attention, nearest sampling, zero padding.
// value:             (6, 14960, 8, 32)  f32
// sampling_locations:(6, 40000, 8, 4, 4, 2) f32
// out:               (6, 40000, 256)    f32
//
// Mapping: 8 lanes per (b,q,h); lane owns float4 of D (dg = lane&7).
// Gather per sample = 128B contiguous across the 8 lanes.

#define BS 6
#define NQ 40000
#define NH 8
#define HD 32
#define NK 14960

__global__ __launch_bounds__(256)
void msda_kernel(const float* __restrict__ value,
                 const float* __restrict__ loc,
                 float* __restrict__ out) {
    constexpr int Wl[4]  = {176, 88, 44, 22};
    constexpr int Hl[4]  = {64, 32, 16, 8};
    constexpr int Off[4] = {0, 11264, 14080, 14784};

    const int tid = blockIdx.x * 256 + threadIdx.x;   // grid sized exactly
    const int dg  = tid & 7;          // which float4 of D
    const int g   = tid >> 3;         // (b*NQ+q)*NH + h
    const int h   = g & 7;
    const int bq  = g >> 3;           // b*NQ + q
    const int b   = bq / NQ;          // compiler emits magic-mul

    const float4* lp = (const float4*)(loc + (size_t)g * 32);
    // value element (b, key, h, d): ((b*NK + key)*NH + h)*HD + d
    const float* vbase = value + (size_t)b * (NK * NH * HD) + h * HD + dg * 4;

    float4 acc = make_float4(0.f, 0.f, 0.f, 0.f);

    #pragma unroll
    for (int l = 0; l < 4; ++l) {
        const int   W  = Wl[l], Hh = Hl[l], off = Off[l];
        const float wf = (float)W, hf = (float)Hh;
        #pragma unroll
        for (int i = 0; i < 2; ++i) {
            const float4 xy2 = lp[l * 2 + i];   // two (x,y) points
            #pragma unroll
            for (int j = 0; j < 2; ++j) {
                const float px = j ? xy2.z : xy2.x;
                const float py = j ? xy2.w : xy2.y;
                // Replicate reference FP sequence exactly:
                // g = 2*loc - 1;  x = ((g+1)*w)*0.5 - 0.5;  ix = rint(x)
                const float gx = 2.0f * px - 1.0f;
                const float gy = 2.0f * py - 1.0f;
                const float x  = ((gx + 1.0f) * wf) * 0.5f - 0.5f;
                const float y  = ((gy + 1.0f) * hf) * 0.5f - 0.5f;
                const float fx = rintf(x);      // v_rndne_f32: half-to-even (matches np.rint)
                const float fy = rintf(y);
                const int ix = (int)fx;
                const int iy = (int)fy;
                const bool valid = (ix >= 0) & (ix < W) & (iy >= 0) & (iy < Hh);
                const int cx = min(max(ix, 0), W - 1);
                const int cy = min(max(iy, 0), Hh - 1);
                const int key = off + cy * W + cx;
                const float4 v = *(const float4*)(vbase + (size_t)key * (NH * HD));
                if (valid) {
                    acc.x += v.x; acc.y += v.y; acc.z += v.z; acc.w += v.w;
                }
            }
        }
    }

    // out (b, q, h*HD + d): contiguous float4 per lane, 2KB per wave
    *(float4*)(out + (size_t)g * HD + dg * 4) = acc;
}

extern "C" void kernel_launch(void* const* d_in, const int* in_sizes, int n_in,
                              void* d_out, int out_size, void* d_ws, size_t ws_size,
                              hipStream_t stream) {
    const float* value = (const float*)d_in[0];
    // d_in[1] = value_spatial_shapes (int32) — constants, hardcoded in-kernel
    const float* loc   = (const float*)d_in[2];
    float* out = (float*)d_out;

    // threads = BS*NQ*NH*8 = 15,360,000 = 60000 blocks * 256 (exact)
    msda_kernel<<<60000, 256, 0, stream>>>(value, loc, out);
}